// Round 6
// baseline (555.977 us; speedup 1.0000x reference)
//
#include <hip/hip_runtime.h>
#include <hip/hip_bf16.h>
#include <stdint.h>

#define B_ 4096
#define D_ 2048
#define U_ 2048
#define K_ 4096   // D + U
#define N_ 8192   // 4 * U

typedef __bf16 bf16x8 __attribute__((ext_vector_type(8)));
typedef float floatx4 __attribute__((ext_vector_type(4)));
typedef unsigned short ushort8 __attribute__((ext_vector_type(8)));

__device__ __forceinline__ unsigned short f2bf(float f) {
    union { float f; unsigned int u; } v; v.f = f;
    unsigned int u = v.u;
    unsigned int r = (u + 0x7fffu + ((u >> 16) & 1u)) >> 16;  // round-nearest-even
    return (unsigned short)r;
}

__device__ __forceinline__ float bf2f(unsigned short b) {
    union { unsigned int u; float f; } v;
    v.u = ((unsigned int)b) << 16;
    return v.f;
}

__device__ __forceinline__ float sigmoid_(float x) {
    return 1.0f / (1.0f + __expf(-x));
}
__device__ __forceinline__ float tanh_(float x) {
    return 1.0f - 2.0f / (__expf(2.0f * x) + 1.0f);
}

// ---------------------------------------------------------------------------
// Kernel 1: pack [x | h] -> Abf[4096][4096] bf16 (row-major, K contiguous)
// ---------------------------------------------------------------------------
__global__ void k_convA(const float* __restrict__ x, const float* __restrict__ h,
                        unsigned short* __restrict__ Abf) {
    int t = blockIdx.x * blockDim.x + threadIdx.x;   // one float4 each
    long e = (long)t * 4;
    int b = (int)(e >> 12);       // / 4096
    int k = (int)(e & 4095);
    const float* src = (k < D_) ? (x + (size_t)b * D_ + k)
                                : (h + (size_t)b * U_ + (k - D_));
    float4 v = *(const float4*)src;
    ushort4 o;
    o.x = f2bf(v.x); o.y = f2bf(v.y); o.z = f2bf(v.z); o.w = f2bf(v.w);
    *(ushort4*)(Abf + e) = o;
}

// ---------------------------------------------------------------------------
// Kernel 2: transpose weights -> Bt[8192][4096] bf16 (plain: row = g*2048+u)
// ---------------------------------------------------------------------------
__global__ __launch_bounds__(256) void k_convB(
        const float* __restrict__ Wx0, const float* __restrict__ Wx1,
        const float* __restrict__ Wx2, const float* __restrict__ Wx3,
        const float* __restrict__ Wh0, const float* __restrict__ Wh1,
        const float* __restrict__ Wh2, const float* __restrict__ Wh3,
        unsigned short* __restrict__ Bt) {
    __shared__ float tile[64][65];   // +1 pad: <=2-way (free) conflicts
    const int g  = blockIdx.z;
    const int k0 = blockIdx.x * 64;
    const int u0 = blockIdx.y * 64;
    const int t  = threadIdx.x;
    const float* W;
    if (k0 < D_) {
        W = (g == 0 ? Wx0 : g == 1 ? Wx1 : g == 2 ? Wx2 : Wx3) + (size_t)k0 * U_;
    } else {
        W = (g == 0 ? Wh0 : g == 1 ? Wh1 : g == 2 ? Wh2 : Wh3) + (size_t)(k0 - D_) * U_;
    }
    {
        const int kr_b = t >> 4;          // 0..15
        const int uc   = (t & 15) * 4;    // 0..60
        #pragma unroll
        for (int p = 0; p < 4; ++p) {
            int kr = p * 16 + kr_b;
            float4 v = *(const float4*)(W + (size_t)kr * U_ + u0 + uc);
            tile[kr][uc + 0] = v.x;
            tile[kr][uc + 1] = v.y;
            tile[kr][uc + 2] = v.z;
            tile[kr][uc + 3] = v.w;
        }
    }
    __syncthreads();
    {
        const int kc = (t & 7) * 8;       // 0..56
        #pragma unroll
        for (int p = 0; p < 2; ++p) {
            int u_idx = p * 32 + (t >> 3);          // 0..63
            int u = u0 + u_idx;
            int nrow = g * U_ + u;                   // plain mapping
            ushort8 o;
            #pragma unroll
            for (int kk = 0; kk < 8; ++kk)
                o[kk] = f2bf(tile[kc + kk][u_idx]);
            *(ushort8*)(Bt + (size_t)nrow * K_ + k0 + kc) = o;
        }
    }
}

// ---------------------------------------------------------------------------
// Kernel 3: GEMM  Z = Abf * Bt^T — R5 BK=64 two-panel core + XOR-swizzled
// LDS chunk placement. Row R's 16B k-chunk q lives at slot q^((R>>1)&3):
//   staging lane l loads global chunk (l&3)^((l>>3)&3) of its row (free),
//   fragment reads add lane-constant (quad^((r>>1)&3))*8.
// Bank-sets go from 8-way (4 extra cyc/ds_read_b128 measured) to 2-way (free).
// ---------------------------------------------------------------------------
__device__ __forceinline__ void gload16(const unsigned short* g, unsigned short* l) {
    __builtin_amdgcn_global_load_lds(
        (const __attribute__((address_space(1))) void*)g,
        (__attribute__((address_space(3))) void*)l, 16, 0, 0);
}

__global__ __launch_bounds__(256) void k_gemm(const unsigned short* __restrict__ A,
                                              const unsigned short* __restrict__ Bt,
                                              unsigned short* __restrict__ Z) {
    // XCD-aware swizzle (kept from R4)
    const int id    = blockIdx.x;
    const int xcd   = id & 7;
    const int s     = id >> 3;
    const int m_blk = (xcd << 2) | (s & 3);   // 0..31
    const int n_blk = s >> 2;                 // 0..63
    const int m0 = m_blk * 128;
    const int n0 = n_blk * 128;

    __shared__ __align__(16) unsigned short As[2][128 * 32];
    __shared__ __align__(16) unsigned short Bs[2][128 * 32];
    const int tid = threadIdx.x;
    const int w   = tid >> 6;      // wave 0..3
    const int l   = tid & 63;      // lane

    // staging: lane l covers row (w*16 + l>>2), global k-chunk (l&3)^((l>>3)&3)
    const int qg = (l & 3) ^ ((l >> 3) & 3);
    const unsigned short* gA = A  + (size_t)(m0 + w * 16 + (l >> 2)) * K_ + qg * 8;
    const unsigned short* gB = Bt + (size_t)(n0 + w * 16 + (l >> 2)) * K_ + qg * 8;
    unsigned short* lA0 = As[0] + w * 512;   // wave-uniform LDS bases
    unsigned short* lA1 = As[1] + w * 512;
    unsigned short* lB0 = Bs[0] + w * 512;
    unsigned short* lB1 = Bs[1] + w * 512;

    const int r     = l & 15;
    const int quad  = l >> 4;
    const int m_off = (w & 1) * 64;
    const int n_off = (w >> 1) * 64;
    const int sw    = (quad ^ ((r >> 1) & 3)) * 8;   // lane-constant read swizzle

    floatx4 acc[4][4];
    #pragma unroll
    for (int i = 0; i < 4; ++i)
        #pragma unroll
        for (int j = 0; j < 4; ++j)
            #pragma unroll
            for (int e = 0; e < 4; ++e) acc[i][j][e] = 0.f;

    for (int k0 = 0; k0 < K_; k0 += 64) {
        __syncthreads();
        // panel 0: k in [k0, k0+32)
        gload16(gA + k0,                        lA0);
        gload16(gA + k0 + (size_t)64 * K_,      lA0 + 2048);
        gload16(gB + k0,                        lB0);
        gload16(gB + k0 + (size_t)64 * K_,      lB0 + 2048);
        // panel 1: k in [k0+32, k0+64)
        gload16(gA + k0 + 32,                   lA1);
        gload16(gA + k0 + 32 + (size_t)64 * K_, lA1 + 2048);
        gload16(gB + k0 + 32,                   lB1);
        gload16(gB + k0 + 32 + (size_t)64 * K_, lB1 + 2048);
        __syncthreads();

        #pragma unroll
        for (int p = 0; p < 2; ++p) {
            bf16x8 af[4], bfv[4];
            #pragma unroll
            for (int i = 0; i < 4; ++i)
                af[i] = *(const bf16x8*)(As[p] + ((m_off + i * 16 + r) * 32 + sw));
            #pragma unroll
            for (int j = 0; j < 4; ++j)
                bfv[j] = *(const bf16x8*)(Bs[p] + ((n_off + j * 16 + r) * 32 + sw));
            #pragma unroll
            for (int i = 0; i < 4; ++i)
                #pragma unroll
                for (int j = 0; j < 4; ++j)
                    acc[i][j] = __builtin_amdgcn_mfma_f32_16x16x32_bf16(
                        af[i], bfv[j], acc[i][j], 0, 0, 0);
        }
    }

    // epilogue: C/D layout col = lane&15, row = quad*4 + reg  [m89/m91 verified]
    #pragma unroll
    for (int i = 0; i < 4; ++i) {
        #pragma unroll
        for (int j = 0; j < 4; ++j) {
            int col = n0 + n_off + j * 16 + r;
            #pragma unroll
            for (int e = 0; e < 4; ++e) {
                int row = m0 + m_off + i * 16 + quad * 4 + e;
                Z[(size_t)row * N_ + col] = f2bf(acc[i][j][e]);
            }
        }
    }
}

// ---------------------------------------------------------------------------
// Kernel 4: gate fusion. Reads Z(bf16), c, biases; writes h_new, c_new (fp32)
// ---------------------------------------------------------------------------
__global__ void k_gates(const unsigned short* __restrict__ Z, const float* __restrict__ c,
                        const float* __restrict__ bfp, const float* __restrict__ bip,
                        const float* __restrict__ bop, const float* __restrict__ bgp,
                        float* __restrict__ hout, float* __restrict__ cout) {
    int t = blockIdx.x * blockDim.x + threadIdx.x;   // 4 u-values each
    long e = (long)t * 4;
    int b = (int)(e >> 11);      // / 2048
    int u = (int)(e & 2047);
    const size_t zr = (size_t)b * N_;
    ushort4 zf4 = *(const ushort4*)(Z + zr + u);
    ushort4 zi4 = *(const ushort4*)(Z + zr + U_ + u);
    ushort4 zo4 = *(const ushort4*)(Z + zr + 2 * U_ + u);
    ushort4 zg4 = *(const ushort4*)(Z + zr + 3 * U_ + u);
    float4 bfv = *(const float4*)(bfp + u);
    float4 biv = *(const float4*)(bip + u);
    float4 bov = *(const float4*)(bop + u);
    float4 bgv = *(const float4*)(bgp + u);
    float4 cv  = *(const float4*)(c + e);

    float zf[4] = {bf2f(zf4.x), bf2f(zf4.y), bf2f(zf4.z), bf2f(zf4.w)};
    float zi[4] = {bf2f(zi4.x), bf2f(zi4.y), bf2f(zi4.z), bf2f(zi4.w)};
    float zo[4] = {bf2f(zo4.x), bf2f(zo4.y), bf2f(zo4.z), bf2f(zo4.w)};
    float zg[4] = {bf2f(zg4.x), bf2f(zg4.y), bf2f(zg4.z), bf2f(zg4.w)};
    float bff[4] = {bfv.x, bfv.y, bfv.z, bfv.w};
    float bif[4] = {biv.x, biv.y, biv.z, biv.w};
    float bof[4] = {bov.x, bov.y, bov.z, bov.w};
    float bgf[4] = {bgv.x, bgv.y, bgv.z, bgv.w};
    float cf[4]  = {cv.x, cv.y, cv.z, cv.w};

    float hh[4], cc[4];
    #pragma unroll
    for (int q = 0; q < 4; ++q) {
        float f = sigmoid_(zf[q] + bff[q]);
        float i = sigmoid_(zi[q] + bif[q]);
        float o = sigmoid_(zo[q] + bof[q]);
        float g = tanh_(zg[q] + bgf[q]);
        float cn = f * cf[q] + i * g;
        cc[q] = cn;
        hh[q] = o * tanh_(cn);
    }
    float4 ho, co;
    ho.x = hh[0]; ho.y = hh[1]; ho.z = hh[2]; ho.w = hh[3];
    co.x = cc[0]; co.y = cc[1]; co.z = cc[2]; co.w = cc[3];
    *(float4*)(hout + e) = ho;
    *(float4*)(cout + e) = co;
}

// ---------------------------------------------------------------------------
extern "C" void kernel_launch(void* const* d_in, const int* in_sizes, int n_in,
                              void* d_out, int out_size, void* d_ws, size_t ws_size,
                              hipStream_t stream) {
    const float* x   = (const float*)d_in[0];
    const float* h   = (const float*)d_in[1];
    const float* c   = (const float*)d_in[2];
    const float* Wxf = (const float*)d_in[3];
    const float* Wxi = (const float*)d_in[4];
    const float* Wxo = (const float*)d_in[5];
    const float* Wxg = (const float*)d_in[6];
    const float* bf  = (const float*)d_in[7];
    const float* bi  = (const float*)d_in[8];
    const float* bo  = (const float*)d_in[9];
    const float* bg  = (const float*)d_in[10];
    const float* Whf = (const float*)d_in[11];
    const float* Whi = (const float*)d_in[12];
    const float* Who = (const float*)d_in[13];
    const float* Whg = (const float*)d_in[14];
    float* out = (float*)d_out;

    // workspace layout: Abf (33.5 MB) | Bt (67 MB) | Z bf16 (67 MB)
    unsigned short* Abf = (unsigned short*)d_ws;
    unsigned short* Bt  = Abf + (size_t)B_ * K_;
    unsigned short* Z   = Bt + (size_t)N_ * K_;

    k_convA<<<(B_ * K_ / 4) / 256, 256, 0, stream>>>(x, h, Abf);
    k_convB<<<dim3(K_ / 64, U_ / 64, 4), 256, 0, stream>>>(
        Wxf, Wxi, Wxo, Wxg, Whf, Whi, Who, Whg, Bt);
    k_gemm<<<dim3((B_ / 128) * (N_ / 128)), 256, 0, stream>>>(Abf, Bt, Z);
    k_gates<<<(B_ * U_ / 4) / 256, 256, 0, stream>>>(
        Z, c, bf, bi, bo, bg, out, out + (size_t)B_ * U_);
}